// Round 2
// baseline (6301.154 us; speedup 1.0000x reference)
//
#include <hip/hip_runtime.h>
#include <hip/hip_fp16.h>

typedef _Float16 f16;
typedef _Float16 f16x8 __attribute__((ext_vector_type(8)));
typedef float f32x16 __attribute__((ext_vector_type(16)));

#define B_N 64
#define T_N 512
#define I_N 64
#define H_N 1024
#define DSTEPS 48
#define TOTSTEPS 560
#define NWG 64

// ---- ws layout (bytes) ----
#define OFF_WHHE 0ull
#define SZ_WHH   (4096ull*1024*2)          // 8 MB
#define OFF_WHHD (OFF_WHHE + SZ_WHH)
#define OFF_WIHE (OFF_WHHD + SZ_WHH)
#define SZ_WIH   (4096ull*64*2)            // 512 KB
#define OFF_WIHD (OFF_WIHE + SZ_WIH)
#define OFF_WFC  (OFF_WIHD + SZ_WIH)
#define SZ_WFC   (64ull*1024*2)            // 128 KB
#define OFF_XP   (OFF_WFC + SZ_WFC)
#define SZ_XP    (512ull*4096*2)           // 4 MB
#define OFF_Y0   (OFF_XP + SZ_XP)
#define SZ_Y0    (4096ull*2)
#define OFF_BE   (OFF_Y0 + SZ_Y0)
#define OFF_BD   (OFF_BE + 4096ull*4)
#define OFF_FLAGS (OFF_BD + 4096ull*4)
#define SZ_FLAGS (561ull*64*4)
#define OFF_H    ((OFF_FLAGS + SZ_FLAGS + 255ull) & ~255ull)
// h[t] (t in 1..560): 64k f16 each, at OFF_H + (t-1)*131072

// LDS layout (dynamic, 147968 B total):
//   whh_lds : f16 [65536]  (128 KB)  -- this WG's Whh slice, fragment-linear
//   lds_g   : f32 [4096]   (16 KB)   -- gates, XOR-swizzled [n][ (m+n)&63 ]
//   bias_s  : f32 [2][64]  (512 B)
#define LDS_BYTES (131072 + 16384 + 512)

// ============================ prologue: pack to fp16 fragment-linear ============================
__global__ void prologue(const float* __restrict__ x, const float* __restrict__ y0,
    const float* __restrict__ wihE, const float* __restrict__ whhE,
    const float* __restrict__ bihE, const float* __restrict__ bhhE,
    const float* __restrict__ wihD, const float* __restrict__ whhD,
    const float* __restrict__ bihD, const float* __restrict__ bhhD,
    const float* __restrict__ wfc, char* __restrict__ ws)
{
  const long long gid = (long long)blockIdx.x * 256 + threadIdx.x;
  const long long gsz = (long long)gridDim.x * 256;
  f16* whhEp = (f16*)(ws + OFF_WHHE);
  f16* whhDp = (f16*)(ws + OFF_WHHD);
  f16* wihEp = (f16*)(ws + OFF_WIHE);
  f16* wihDp = (f16*)(ws + OFF_WIHD);
  f16* wfcp  = (f16*)(ws + OFF_WFC);
  f16* xp    = (f16*)(ws + OFF_XP);
  f16* y0p   = (f16*)(ws + OFF_Y0);
  float* be  = (float*)(ws + OFF_BE);
  float* bd  = (float*)(ws + OFF_BD);

  // Whh packs: [w][wn][kk][lane][8]  (4,194,304 f16 each)
  for (long long idx = gid; idx < 4194304ll; idx += gsz) {
    int j = idx & 7, l = (idx >> 3) & 63, kk = (idx >> 9) & 63, wn = (idx >> 15) & 1, w = (int)(idx >> 16);
    int nl = wn * 32 + (l & 31);
    int grow = (nl >> 4) * 1024 + w * 16 + (nl & 15);   // gate*1024 + unit
    int k = kk * 16 + ((l >> 5) << 3) + j;
    whhEp[idx] = (f16)whhE[(long long)grow * 1024 + k];
    whhDp[idx] = (f16)whhD[(long long)grow * 1024 + k];
  }
  // Wih packs: [w][wn][kkx(4)][lane][8]  (262,144 each)
  for (long long idx = gid; idx < 262144ll; idx += gsz) {
    int j = idx & 7, l = (idx >> 3) & 63, kkx = (idx >> 9) & 3, wn = (idx >> 11) & 1, w = (int)(idx >> 12);
    int nl = wn * 32 + (l & 31);
    int grow = (nl >> 4) * 1024 + w * 16 + (nl & 15);
    int k = kkx * 16 + ((l >> 5) << 3) + j;
    wihEp[idx] = (f16)wihE[grow * 64 + k];
    wihDp[idx] = (f16)wihD[grow * 64 + k];
  }
  // Wfc pack: [wn][kk][lane][8]  (65,536)
  for (long long idx = gid; idx < 65536ll; idx += gsz) {
    int j = idx & 7, l = (idx >> 3) & 63, kk = (idx >> 9) & 63, wn = (idx >> 15) & 1;
    int o = wn * 32 + (l & 31);
    int k = kk * 16 + ((l >> 5) << 3) + j;
    wfcp[idx] = (f16)wfc[o * 1024 + k];
  }
  // x pack: [t][kkx(4)][b][16]  (2,097,152)
  for (long long idx = gid; idx < 2097152ll; idx += gsz) {
    int kw = idx & 15, b = (idx >> 4) & 63, kkx = (idx >> 10) & 3, t = (int)(idx >> 12);
    xp[idx] = (f16)x[(long long)b * 32768 + t * 64 + kkx * 16 + kw];
  }
  // y0 pack: [kkx][b][16]  (4096)
  for (long long idx = gid; idx < 4096ll; idx += gsz) {
    int kw = idx & 15, b = (idx >> 4) & 63, kkx = (idx >> 10) & 3;
    y0p[idx] = (f16)y0[b * 64 + kkx * 16 + kw];
  }
  // combined biases
  for (long long idx = gid; idx < 4096ll; idx += gsz) {
    be[idx] = bihE[idx] + bhhE[idx];
    bd[idx] = bihD[idx] + bhhD[idx];
  }
}

// ============================ persistent LSTM kernel ============================
__device__ __forceinline__ float sigf(float x) { return 1.0f / (1.0f + __expf(-x)); }
__device__ __forceinline__ float tanhfast(float x) {
  x = fminf(fmaxf(x, -15.f), 15.f);
  float e = __expf(2.0f * x);
  return (e - 1.0f) / (e + 1.0f);
}

#define MFMA(a,b,c) __builtin_amdgcn_mfma_f32_32x32x16_f16((a),(b),(c),0,0,0)
// gates buffer, XOR-swizzled: entry (n,m) at n*64 + ((m+n)&63); writes and reads are <=2 lanes/bank
#define LG(n,m) lds_g[((n) << 6) + ((((m) + (n))) & 63)]

__launch_bounds__(256)
__global__ void lstm_persist(char* __restrict__ ws, float* __restrict__ out,
                             const float* __restrict__ bfc)
{
  const int w    = blockIdx.x;      // owns hidden units [w*16, w*16+16)
  const int tid  = threadIdx.x;
  const int lane = tid & 63;
  const int wave = tid >> 6;
  const int wm   = wave & 1;        // M-half (batch 0..31 / 32..63)
  const int wn   = wave >> 1;       // N-half (gate rows 0..31 / 32..63)

  const f16* whhEp = (const f16*)(ws + OFF_WHHE) + (size_t)w * 65536;
  const f16* whhDp = (const f16*)(ws + OFF_WHHD) + (size_t)w * 65536;
  const f16* wihEp = (const f16*)(ws + OFF_WIHE) + (size_t)w * 4096;
  const f16* wihDp = (const f16*)(ws + OFF_WIHD) + (size_t)w * 4096;
  const f16* wfcp  = (const f16*)(ws + OFF_WFC);
  const f16* xp    = (const f16*)(ws + OFF_XP);
  const f16* y0p   = (const f16*)(ws + OFF_Y0);
  const float* be  = (const float*)(ws + OFF_BE);
  const float* bd  = (const float*)(ws + OFF_BD);
  unsigned* flags  = (unsigned*)(ws + OFF_FLAGS);
  f16* hb          = (f16*)(ws + OFF_H);           // h[t] at (t-1)*65536 elements

  extern __shared__ char smem[];
  f16*   whh_lds = (f16*)smem;                       // 128 KB
  float* lds_g   = (float*)(smem + 131072);          // 16 KB swizzled
  float* bias_s  = (float*)(smem + 131072 + 16384);  // [2][64]

  if (tid < 64) {
    int g = tid >> 4, u = tid & 15;
    bias_s[tid]      = be[g * 1024 + w * 16 + u];
    bias_s[64 + tid] = bd[g * 1024 + w * 16 + u];
  }
  // stage encoder Whh slice into LDS (verbatim fragment-linear copy)
  for (int i = tid; i < 8192; i += 256)
    *(f16x8*)(whh_lds + (size_t)i * 8) = *(const f16x8*)(whhEp + (size_t)i * 8);

  float c0 = 0.f, c1 = 0.f, c2 = 0.f, c3 = 0.f;
  __syncthreads();

  // A-fragment offset within a [64b][16k] block: row=wm*32+(lane&31), khalf=(lane>>5)
  const int aoff = (wm * 32 + (lane & 31)) * 16 + (lane >> 5) * 8;
  const int boff = lane * 8;          // lane-linear packed B
  const int bsel = tid & 63;          // batch this thread updates
  const int ug   = tid >> 6;          // unit group (4 units)

  for (int t = 0; t < TOTSTEPS; ++t) {
    const bool enc = (t < T_N);
    const f16* wih  = enc ? wihEp : wihDp;
    const f16* xblk = enc ? (xp + (size_t)t * 4096) : y0p;

    if (t == T_N) {
      // all waves passed the end-of-step-511 barrier -> safe to overwrite, then sync before use
      for (int i = tid; i < 8192; i += 256)
        *(f16x8*)(whh_lds + (size_t)i * 8) = *(const f16x8*)(whhDp + (size_t)i * 8);
      __syncthreads();
    }

    f32x16 acc;
#pragma unroll
    for (int i = 0; i < 16; ++i) acc[i] = 0.f;

    // input projection, K=64
#pragma unroll
    for (int kkx = 0; kkx < 4; ++kkx) {
      f16x8 a = *(const f16x8*)(xblk + kkx * 1024 + aoff);
      f16x8 b = *(const f16x8*)(wih + (wn * 4 + kkx) * 512 + boff);
      acc = MFMA(a, b, acc);
    }

    if (t > 0) {
      // wait for all 64 h(t) slices
      unsigned* fl = flags + (size_t)t * 64;
      int ok;
      do {
        unsigned v = __hip_atomic_load(fl + lane, __ATOMIC_RELAXED, __HIP_MEMORY_SCOPE_AGENT);
        ok = (v == 1u);
      } while (__syncthreads_and(ok) == 0);

      const f16* hblk = hb + (size_t)(t - 1) * 65536;
#pragma unroll 4
      for (int kk = 0; kk < 64; ++kk) {
        f16x8 a = *(const f16x8*)(hblk + kk * 1024 + aoff);
        f16x8 b = *(const f16x8*)(whh_lds + (wn * 64 + kk) * 512 + boff);
        acc = MFMA(a, b, acc);
      }
    }

    // write full gate quadrant to swizzled LDS
    {
      const int n0 = wn * 32 + (lane & 31);
      const int mb = wm * 32 + ((lane >> 5) << 2);
#pragma unroll
      for (int r = 0; r < 16; ++r) {
        const int m = mb + (r & 3) + ((r >> 2) << 3);
        LG(n0, m) = acc[r];
      }
    }
    __syncthreads();

    // LSTM cell update: thread -> (batch bsel, units ug*4..+3), c kept in fp32 regs
    const float* bs = bias_s + (enc ? 0 : 64);
    union { unsigned long long u64; f16 h4[4]; } hu;
    float cc[4] = {c0, c1, c2, c3};
#pragma unroll
    for (int j = 0; j < 4; ++j) {
      const int u = ug * 4 + j;
      float ig = LG(u, bsel)      + bs[u];
      float fg = LG(16 + u, bsel) + bs[16 + u];
      float gg = LG(32 + u, bsel) + bs[32 + u];
      float og = LG(48 + u, bsel) + bs[48 + u];
      float cn = sigf(fg) * cc[j] + sigf(ig) * tanhfast(gg);
      cc[j] = cn;
      hu.h4[j] = (f16)(sigf(og) * tanhfast(cn));
    }
    c0 = cc[0]; c1 = cc[1]; c2 = cc[2]; c3 = cc[3];

    // write-through h(t+1) slice (device-coherent), then release flag
    {
      f16* dst = hb + (size_t)t * 65536 + w * 1024 + bsel * 16 + ug * 4;
      unsigned long long addr = (unsigned long long)(size_t)dst;
      asm volatile("global_store_dwordx2 %0, %1, off sc0 sc1" : : "v"(addr), "v"(hu.u64) : "memory");
    }
    __syncthreads();   // all waves' stores issued before flag (release below drains)
    if (tid == 0) {
      __hip_atomic_store(flags + (size_t)(t + 1) * 64 + w, 1u,
                         __ATOMIC_RELEASE, __HIP_MEMORY_SCOPE_AGENT);
    }
  }

  // ---- FC epilogue: WG w<48 computes out[:, w*64 .. w*64+64) from decoder h at t=512+w ----
  if (w < DSTEPS) {
    const int s = T_N + 1 + w;   // flag index for h produced at step t=512+w
    unsigned* fl = flags + (size_t)s * 64;
    int ok;
    do {
      unsigned v = __hip_atomic_load(fl + lane, __ATOMIC_RELAXED, __HIP_MEMORY_SCOPE_AGENT);
      ok = (v == 1u);
    } while (__syncthreads_and(ok) == 0);

    f32x16 acc;
#pragma unroll
    for (int i = 0; i < 16; ++i) acc[i] = 0.f;
    const f16* hblk = hb + (size_t)(s - 1) * 65536;
#pragma unroll 4
    for (int kk = 0; kk < 64; ++kk) {
      f16x8 a = *(const f16x8*)(hblk + kk * 1024 + aoff);
      f16x8 b = *(const f16x8*)(wfcp + (wn * 64 + kk) * 512 + boff);
      acc = MFMA(a, b, acc);
    }
    {
      const int n0 = wn * 32 + (lane & 31);
      const int mb = wm * 32 + ((lane >> 5) << 2);
#pragma unroll
      for (int r = 0; r < 16; ++r) {
        const int m = mb + (r & 3) + ((r >> 2) << 3);
        LG(n0, m) = acc[r];
      }
    }
    __syncthreads();
    // each thread covers ALL 16 features of its quarter: f = ug*16 .. ug*16+15
    const int fb = ug * 16;
#pragma unroll
    for (int q = 0; q < 4; ++q) {
      const int f = fb + q * 4;
      float t0 = LG(f + 0, bsel) + bfc[f + 0];
      float t1 = LG(f + 1, bsel) + bfc[f + 1];
      float t2 = LG(f + 2, bsel) + bfc[f + 2];
      float t3 = LG(f + 3, bsel) + bfc[f + 3];
      *(float4*)(out + (size_t)bsel * 3072 + w * 64 + f) = make_float4(t0, t1, t2, t3);
    }
  }
}

// ============================ launch ============================
extern "C" void kernel_launch(void* const* d_in, const int* in_sizes, int n_in,
                              void* d_out, int out_size, void* d_ws, size_t ws_size,
                              hipStream_t stream) {
  const float* x    = (const float*)d_in[0];
  const float* y0   = (const float*)d_in[1];
  const float* wihE = (const float*)d_in[2];
  const float* whhE = (const float*)d_in[3];
  const float* bihE = (const float*)d_in[4];
  const float* bhhE = (const float*)d_in[5];
  const float* wihD = (const float*)d_in[6];
  const float* whhD = (const float*)d_in[7];
  const float* bihD = (const float*)d_in[8];
  const float* bhhD = (const float*)d_in[9];
  const float* wfc  = (const float*)d_in[10];
  const float* bfc  = (const float*)d_in[11];
  char* ws   = (char*)d_ws;
  float* out = (float*)d_out;

  static bool attr_set = false;
  if (!attr_set) {
    (void)hipFuncSetAttribute((const void*)lstm_persist,
                              hipFuncAttributeMaxDynamicSharedMemorySize, LDS_BYTES);
    attr_set = true;
  }

  prologue<<<256, 256, 0, stream>>>(x, y0, wihE, whhE, bihE, bhhE,
                                    wihD, whhD, bihD, bhhD, wfc, ws);
  lstm_persist<<<NWG, 256, LDS_BYTES, stream>>>(ws, out, bfc);
}

// Round 3
// 3407.566 us; speedup vs baseline: 1.8492x; 1.8492x over previous
//
#include <hip/hip_runtime.h>
#include <hip/hip_fp16.h>

typedef _Float16 f16;
typedef _Float16 f16x8 __attribute__((ext_vector_type(8)));
typedef float f32x16 __attribute__((ext_vector_type(16)));

#define T_N 512
#define DSTEPS 48
#define TOTSTEPS 560
#define NWG 64

// ---- ws layout (bytes) ----
#define OFF_WHHE 0ull
#define SZ_WHH   (4096ull*1024*2)          // 8 MB
#define OFF_WHHD (OFF_WHHE + SZ_WHH)
#define OFF_WIHE (OFF_WHHD + SZ_WHH)
#define SZ_WIH   (4096ull*64*2)            // 512 KB
#define OFF_WIHD (OFF_WIHE + SZ_WIH)
#define OFF_WFC  (OFF_WIHD + SZ_WIH)
#define SZ_WFC   (64ull*1024*2)            // 128 KB
#define OFF_XP   (OFF_WFC + SZ_WFC)
#define SZ_XP    (512ull*4096*2)           // 4 MB
#define OFF_Y0   (OFF_XP + SZ_XP)
#define SZ_Y0    (4096ull*2)
#define OFF_BE   (OFF_Y0 + SZ_Y0)
#define OFF_BD   (OFF_BE + 4096ull*4)
#define OFF_FLAGS (OFF_BD + 4096ull*4)
#define SZ_FLAGS (561ull*64*4)
#define OFF_H    ((OFF_FLAGS + SZ_FLAGS + 255ull) & ~255ull)
// h produced at step t: 65536 f16 at OFF_H + t*131072, layout [w_src(64)][b(64)][u(16)]

// ============================ prologue: pack to fp16 fragment-linear ============================
// Fragment indexing for wave (wm, ks):
//   B-frag (Whh): idx = w*65536 + ks*32768 + i*16384 + kk*512 + lane*8 + j
//     maps to Whh[gate*1024 + w*16 + unit][ks*512 + kk*16 + (lane>>5)*8 + j],
//     with n_local = i*32 + (lane&31) = gate*16 + unit
//   Wih frag:     idx = w*4096 + ks*2048 + i*1024 + kx*512 + lane*8 + j
//   Wfc frag:     idx = ks*32768 + i*16384 + kk*512 + lane*8 + j
__global__ void prologue(const float* __restrict__ x, const float* __restrict__ y0,
    const float* __restrict__ wihE, const float* __restrict__ whhE,
    const float* __restrict__ bihE, const float* __restrict__ bhhE,
    const float* __restrict__ wihD, const float* __restrict__ whhD,
    const float* __restrict__ bihD, const float* __restrict__ bhhD,
    const float* __restrict__ wfc, char* __restrict__ ws)
{
  const long long gid = (long long)blockIdx.x * 256 + threadIdx.x;
  const long long gsz = (long long)gridDim.x * 256;
  f16* whhEp = (f16*)(ws + OFF_WHHE);
  f16* whhDp = (f16*)(ws + OFF_WHHD);
  f16* wihEp = (f16*)(ws + OFF_WIHE);
  f16* wihDp = (f16*)(ws + OFF_WIHD);
  f16* wfcp  = (f16*)(ws + OFF_WFC);
  f16* xp    = (f16*)(ws + OFF_XP);
  f16* y0p   = (f16*)(ws + OFF_Y0);
  float* be  = (float*)(ws + OFF_BE);
  float* bd  = (float*)(ws + OFF_BD);

  // Whh packs (4,194,304 f16 each)
  for (long long idx = gid; idx < 4194304ll; idx += gsz) {
    int j = (int)idx & 7, l = (int)(idx >> 3) & 63, kk = (int)(idx >> 9) & 31;
    int i = (int)(idx >> 14) & 1, ks = (int)(idx >> 15) & 1, w = (int)(idx >> 16);
    int nl = i * 32 + (l & 31);
    int grow = (nl >> 4) * 1024 + w * 16 + (nl & 15);
    int k = ks * 512 + kk * 16 + ((l >> 5) << 3) + j;
    whhEp[idx] = (f16)whhE[(long long)grow * 1024 + k];
    whhDp[idx] = (f16)whhD[(long long)grow * 1024 + k];
  }
  // Wih packs (262,144 each)
  for (long long idx = gid; idx < 262144ll; idx += gsz) {
    int j = (int)idx & 7, l = (int)(idx >> 3) & 63, kx = (int)(idx >> 9) & 1;
    int i = (int)(idx >> 10) & 1, ks = (int)(idx >> 11) & 1, w = (int)(idx >> 12);
    int nl = i * 32 + (l & 31);
    int grow = (nl >> 4) * 1024 + w * 16 + (nl & 15);
    int k = (ks * 2 + kx) * 16 + ((l >> 5) << 3) + j;
    wihEp[idx] = (f16)wihE[grow * 64 + k];
    wihDp[idx] = (f16)wihD[grow * 64 + k];
  }
  // Wfc pack (65,536)
  for (long long idx = gid; idx < 65536ll; idx += gsz) {
    int j = (int)idx & 7, l = (int)(idx >> 3) & 63, kk = (int)(idx >> 9) & 31;
    int i = (int)(idx >> 14) & 1, ks = (int)(idx >> 15) & 1;
    int o = i * 32 + (l & 31);
    int k = ks * 512 + kk * 16 + ((l >> 5) << 3) + j;
    wfcp[idx] = (f16)wfc[o * 1024 + k];
  }
  // x pack: [t][kkx(4)][b][16]
  for (long long idx = gid; idx < 2097152ll; idx += gsz) {
    int kw = (int)idx & 15, b = (int)(idx >> 4) & 63, kkx = (int)(idx >> 10) & 3, t = (int)(idx >> 12);
    xp[idx] = (f16)x[(long long)b * 32768 + t * 64 + kkx * 16 + kw];
  }
  // y0 pack: [kkx][b][16]
  for (long long idx = gid; idx < 4096ll; idx += gsz) {
    int kw = (int)idx & 15, b = (int)(idx >> 4) & 63, kkx = (int)(idx >> 10) & 3;
    y0p[idx] = (f16)y0[b * 64 + kkx * 16 + kw];
  }
  // combined biases
  for (long long idx = gid; idx < 4096ll; idx += gsz) {
    be[idx] = bihE[idx] + bhhE[idx];
    bd[idx] = bihD[idx] + bhhD[idx];
  }
}

// ============================ persistent LSTM kernel ============================
__device__ __forceinline__ float sigf(float x) { return 1.0f / (1.0f + __expf(-x)); }
__device__ __forceinline__ float tanhfast(float x) {
  x = fminf(fmaxf(x, -15.f), 15.f);
  float e = __expf(2.0f * x);
  return (e - 1.0f) / (e + 1.0f);
}

#define MFMA(a,b,c) __builtin_amdgcn_mfma_f32_32x32x16_f16((a),(b),(c),0,0,0)

__launch_bounds__(256, 1)
__global__ void lstm_persist(char* __restrict__ ws, float* __restrict__ out,
                             const float* __restrict__ bfc)
{
  const int w    = blockIdx.x;      // owns hidden units [w*16, w*16+16)
  const int tid  = threadIdx.x;
  const int lane = tid & 63;
  const int wave = tid >> 6;
  const int wm   = wave & 1;        // M-half (batch 0..31 / 32..63)
  const int ks   = wave >> 1;       // K-half (h units 0..511 / 512..1023)

  const f16* whhEp = (const f16*)(ws + OFF_WHHE) + (size_t)w * 65536;
  const f16* whhDp = (const f16*)(ws + OFF_WHHD) + (size_t)w * 65536;
  const f16* wihEp = (const f16*)(ws + OFF_WIHE) + (size_t)w * 4096;
  const f16* wihDp = (const f16*)(ws + OFF_WIHD) + (size_t)w * 4096;
  const f16* wfcp  = (const f16*)(ws + OFF_WFC);
  const f16* xp    = (const f16*)(ws + OFF_XP);
  const f16* y0p   = (const f16*)(ws + OFF_Y0);
  const float* be  = (const float*)(ws + OFF_BE);
  const float* bd  = (const float*)(ws + OFF_BD);
  unsigned* flags  = (unsigned*)(ws + OFF_FLAGS);
  f16* hb          = (f16*)(ws + OFF_H);           // h of step t at t*65536

  __shared__ float lds_g[2][64][66];   // [ks][gate-row n][batch m], padded (+2)
  __shared__ float bias_s[2][64];

  if (tid < 64) {
    int g = tid >> 4, u = tid & 15;
    bias_s[0][tid] = be[g * 1024 + w * 16 + u];
    bias_s[1][tid] = bd[g * 1024 + w * 16 + u];
  }

  // A-frag offset inside a [64b][16k] K-block: row=wm*32+(lane&31), khalf=(lane>>5)
  const int aoff = (wm * 32 + (lane & 31)) * 16 + (lane >> 5) * 8;
  const int boff = lane * 8;          // lane-linear packed B
  const int bsel = tid >> 2;          // batch this thread updates (cell phase)
  const int u0   = (tid & 3) * 4;     // first of 4 owned unit-locals

  // ---- Whh B-fragments resident in VGPRs for the whole recurrence ----
  f16x8 bf0[32], bf1[32];             // n-half 0 / 1, kk = 0..31 (local K-half)
#pragma unroll
  for (int kk = 0; kk < 32; ++kk) {
    bf0[kk] = *(const f16x8*)(whhEp + ((size_t)(ks * 2 + 0) * 32 + kk) * 512 + boff);
    bf1[kk] = *(const f16x8*)(whhEp + ((size_t)(ks * 2 + 1) * 32 + kk) * 512 + boff);
  }

  float c0 = 0.f, c1 = 0.f, c2 = 0.f, c3 = 0.f;
  __syncthreads();

#pragma unroll 1
  for (int t = 0; t < TOTSTEPS; ++t) {
    const bool enc = (t < T_N);

    if (t == T_N) {   // swap to decoder weights (registers only, no barrier needed)
#pragma unroll
      for (int kk = 0; kk < 32; ++kk) {
        bf0[kk] = *(const f16x8*)(whhDp + ((size_t)(ks * 2 + 0) * 32 + kk) * 512 + boff);
        bf1[kk] = *(const f16x8*)(whhDp + ((size_t)(ks * 2 + 1) * 32 + kk) * 512 + boff);
      }
    }

    // x-projection operands (decoder: constant y0 block, L2-hot)
    const f16* xblk = enc ? (xp + (size_t)t * 4096) : y0p;
    const f16* wihp = enc ? wihEp : wihDp;
    f16x8 xa0 = *(const f16x8*)(xblk + (ks * 2 + 0) * 1024 + aoff);
    f16x8 xa1 = *(const f16x8*)(xblk + (ks * 2 + 1) * 1024 + aoff);
    f16x8 wf0 = *(const f16x8*)(wihp + ((ks * 2 + 0) * 2 + 0) * 512 + boff);
    f16x8 wf1 = *(const f16x8*)(wihp + ((ks * 2 + 0) * 2 + 1) * 512 + boff);
    f16x8 wf2 = *(const f16x8*)(wihp + ((ks * 2 + 1) * 2 + 0) * 512 + boff);
    f16x8 wf3 = *(const f16x8*)(wihp + ((ks * 2 + 1) * 2 + 1) * 512 + boff);

    // wait for all 64 h(t-1) slices
    if (t > 0) {
      unsigned* fl = flags + (size_t)t * 64;
      int ok;
      do {
        unsigned v = __hip_atomic_load(fl + lane, __ATOMIC_RELAXED, __HIP_MEMORY_SCOPE_AGENT);
        ok = (v == 1u);
      } while (__syncthreads_and(ok) == 0);
    }

    // ---- burst-load this wave's A quarter of h(t-1): 32 x 16B, all in flight ----
    f16x8 af[32];
    if (t > 0) {
      const f16* hblk = hb + (size_t)(t - 1) * 65536;
#pragma unroll
      for (int kk = 0; kk < 32; ++kk)
        af[kk] = *(const f16x8*)(hblk + (size_t)(ks * 32 + kk) * 1024 + aoff);
    }

    f32x16 acc0, acc1;
#pragma unroll
    for (int i = 0; i < 16; ++i) { acc0[i] = 0.f; acc1[i] = 0.f; }
    acc0 = MFMA(xa0, wf0, acc0); acc0 = MFMA(xa1, wf1, acc0);
    acc1 = MFMA(xa0, wf2, acc1); acc1 = MFMA(xa1, wf3, acc1);

    if (t > 0) {
#pragma unroll
      for (int kk = 0; kk < 32; ++kk) {
        acc0 = MFMA(af[kk], bf0[kk], acc0);
        acc1 = MFMA(af[kk], bf1[kk], acc1);
      }
    }

    // K-split partials to LDS
    {
      const int n0 = lane & 31;
      const int mb = wm * 32 + ((lane >> 5) << 2);
#pragma unroll
      for (int r = 0; r < 16; ++r) {
        const int m = mb + (r & 3) + ((r >> 2) << 3);
        lds_g[ks][n0][m]      = acc0[r];
        lds_g[ks][32 + n0][m] = acc1[r];
      }
    }
    __syncthreads();

    // cell update: thread -> (batch bsel, unit-locals u0..u0+3); c in fp32 regs
    const float* bs = enc ? bias_s[0] : bias_s[1];
    union { unsigned long long u64; f16 h4[4]; } hu;
    float cc[4] = {c0, c1, c2, c3};
#pragma unroll
    for (int j = 0; j < 4; ++j) {
      const int u = u0 + j;
      float ig = lds_g[0][u][bsel]      + lds_g[1][u][bsel]      + bs[u];
      float fg = lds_g[0][16 + u][bsel] + lds_g[1][16 + u][bsel] + bs[16 + u];
      float gg = lds_g[0][32 + u][bsel] + lds_g[1][32 + u][bsel] + bs[32 + u];
      float og = lds_g[0][48 + u][bsel] + lds_g[1][48 + u][bsel] + bs[48 + u];
      float cn = sigf(fg) * cc[j] + sigf(ig) * tanhfast(gg);
      cc[j] = cn;
      hu.h4[j] = (f16)(sigf(og) * tanhfast(cn));
    }
    c0 = cc[0]; c1 = cc[1]; c2 = cc[2]; c3 = cc[3];

    // contiguous write-through h slice: thread -> bytes [tid*8, tid*8+8) of the 2KB block
    {
      f16* dst = hb + (size_t)t * 65536 + (size_t)w * 1024 + tid * 4;
      unsigned long long addr = (unsigned long long)(size_t)dst;
      asm volatile("global_store_dwordx2 %0, %1, off sc0 sc1" : : "v"(addr), "v"(hu.u64) : "memory");
    }
    asm volatile("s_waitcnt vmcnt(0)" ::: "memory");   // explicit drain of the asm store
    __syncthreads();
    if (tid == 0) {
      __hip_atomic_store(flags + (size_t)(t + 1) * 64 + w, 1u,
                         __ATOMIC_RELEASE, __HIP_MEMORY_SCOPE_AGENT);
    }
  }

  // ---- FC epilogue: WG w<48 computes out[:, w*64 .. +64) from decoder h of step 512+w ----
  if (w < DSTEPS) {
    const int s = T_N + 1 + w;         // flag index (h produced at step 512+w)
#pragma unroll
    for (int kk = 0; kk < 32; ++kk) {
      bf0[kk] = *(const f16x8*)(wfcp + ((size_t)(ks * 2 + 0) * 32 + kk) * 512 + boff);
      bf1[kk] = *(const f16x8*)(wfcp + ((size_t)(ks * 2 + 1) * 32 + kk) * 512 + boff);
    }
    unsigned* fl = flags + (size_t)s * 64;
    int ok;
    do {
      unsigned v = __hip_atomic_load(fl + lane, __ATOMIC_RELAXED, __HIP_MEMORY_SCOPE_AGENT);
      ok = (v == 1u);
    } while (__syncthreads_and(ok) == 0);

    const f16* hblk = hb + (size_t)(s - 1) * 65536;
    f16x8 af[32];
#pragma unroll
    for (int kk = 0; kk < 32; ++kk)
      af[kk] = *(const f16x8*)(hblk + (size_t)(ks * 32 + kk) * 1024 + aoff);

    f32x16 acc0, acc1;
#pragma unroll
    for (int i = 0; i < 16; ++i) { acc0[i] = 0.f; acc1[i] = 0.f; }
#pragma unroll
    for (int kk = 0; kk < 32; ++kk) {
      acc0 = MFMA(af[kk], bf0[kk], acc0);
      acc1 = MFMA(af[kk], bf1[kk], acc1);
    }
    {
      const int n0 = lane & 31;
      const int mb = wm * 32 + ((lane >> 5) << 2);
#pragma unroll
      for (int r = 0; r < 16; ++r) {
        const int m = mb + (r & 3) + ((r >> 2) << 3);
        lds_g[ks][n0][m]      = acc0[r];
        lds_g[ks][32 + n0][m] = acc1[r];
      }
    }
    __syncthreads();
    // thread -> batch bsel, features fb..fb+15
    const int fb = (tid & 3) * 16;
#pragma unroll
    for (int q = 0; q < 4; ++q) {
      const int f = fb + q * 4;
      float t0 = lds_g[0][f + 0][bsel] + lds_g[1][f + 0][bsel] + bfc[f + 0];
      float t1 = lds_g[0][f + 1][bsel] + lds_g[1][f + 1][bsel] + bfc[f + 1];
      float t2 = lds_g[0][f + 2][bsel] + lds_g[1][f + 2][bsel] + bfc[f + 2];
      float t3 = lds_g[0][f + 3][bsel] + lds_g[1][f + 3][bsel] + bfc[f + 3];
      *(float4*)(out + (size_t)bsel * 3072 + w * 64 + f) = make_float4(t0, t1, t2, t3);
    }
  }
}

// ============================ launch ============================
extern "C" void kernel_launch(void* const* d_in, const int* in_sizes, int n_in,
                              void* d_out, int out_size, void* d_ws, size_t ws_size,
                              hipStream_t stream) {
  const float* x    = (const float*)d_in[0];
  const float* y0   = (const float*)d_in[1];
  const float* wihE = (const float*)d_in[2];
  const float* whhE = (const float*)d_in[3];
  const float* bihE = (const float*)d_in[4];
  const float* bhhE = (const float*)d_in[5];
  const float* wihD = (const float*)d_in[6];
  const float* whhD = (const float*)d_in[7];
  const float* bihD = (const float*)d_in[8];
  const float* bhhD = (const float*)d_in[9];
  const float* wfc  = (const float*)d_in[10];
  const float* bfc  = (const float*)d_in[11];
  char* ws   = (char*)d_ws;
  float* out = (float*)d_out;

  prologue<<<256, 256, 0, stream>>>(x, y0, wihE, whhE, bihE, bhhE,
                                    wihD, whhD, bihD, bhhD, wfc, ws);
  lstm_persist<<<NWG, 256, 0, stream>>>(ws, out, bfc);
}